// Round 4
// baseline (549.732 us; speedup 1.0000x reference)
//
#include <hip/hip_runtime.h>

// GCNN fused kernel for MI355X (gfx950) — counted-vmcnt pipelined GEMM, v2.
// Round-3 post-mortem: inline-asm A-loads ("=v" output) are unsound — HW writes
// the VGPRs ~300-900cy after issue but the compiler models the value as ready at
// the asm statement, so it freely copies garbage across the unrolled rotation.
// Fix: A loads are NORMAL f32x4 loads (compiler inserts exact counted vmcnt —
// it tracks the global_load_lds builtin's counter too), issue slot pinned inside
// sched_barrier(0) regions so our asm vmcnt(3) for B stays exact. Tail fixed:
// no dummy ops, vmcnt(0) at the last chunk.
//  - blocks = (sentence, N-half): 2560 blocks, TPB=512, 8 waves, wave tile 64x32.
//  - B (bf16 Wt) staged per 32-K chunk via global_load_lds, double-buffered,
//    s_waitcnt vmcnt(3) in steady state (never drained mid-loop).
//  - A (f32 rep) chunk loaded 2 regions ahead into registers; cvt+gate-fused
//    ds_write into a 3-slot XOR-swizzled LDS ring.

#define BNK   1280
#define LTOK  64
#define DIN   512
#define DOUT  256
#define NREL  40
#define TPB   512
#define PSTR  132          // Pin/Psf row stride (bf16 elems)

// LDS map (bytes):
#define ABUF_OFF   0        // 3 slots * 4096   (A chunk: 256 units * 16B)
#define BBUF_OFF   12288    // 2 slots * 16384  (B chunk: 1024 units * 16B)
#define WGI_OFF    45056    // 2048
#define WGS_OFF    47104    // 2048
#define WINL_OFF   49152
#define WSFL_OFF   49408
#define MSKL_OFF   49664
#define HDL_OFF    49920
#define LBL_OFF    50176
#define GLD_OFF    50432    // 512
#define AMD_OFF    50944
#define ALD_OFF    51200
#define BGL_OFF    51456    // 160
#define PIN_OFF    0        // 16896 (union with ABUF/BBUF, GEMM done)
#define PSF_OFF    16896    // 16896
#define SMEM_BYTES 51712

typedef __attribute__((ext_vector_type(4))) float f32x4;
typedef __attribute__((ext_vector_type(8))) short s16x8;

__device__ __forceinline__ unsigned short f2bf(float f) {
  unsigned u = __float_as_uint(f);
  unsigned r = (u + 0x7FFFu + ((u >> 16) & 1u)) >> 16;
  return (unsigned short)r;
}
__device__ __forceinline__ float bf2f(unsigned short h) {
  return __uint_as_float(((unsigned)h) << 16);
}
__device__ __forceinline__ float sigmoidf_(float x) {
  return 1.0f / (1.0f + __expf(-x));
}

// ---------------- kernel 0: W_cat -> bf16, transposed to [cat_col][k] ----------------
__global__ __launch_bounds__(256) void wprep_kernel(const float* __restrict__ W_in,
                                                    const float* __restrict__ W_self,
                                                    unsigned short* __restrict__ Wt) {
  __shared__ float tile[32][33];
  const int t  = threadIdx.x;
  const int c0 = (blockIdx.x & 15) * 32;
  const int k0 = (blockIdx.x >> 4) * 32;
  const float* src = (c0 < DOUT) ? W_in : W_self;
  const int cadj   = (c0 < DOUT) ? c0 : (c0 - DOUT);
  {
    const int kk = t >> 3;
    const int cc = (t & 7) * 4;
    const float4 v = *(const float4*)(src + (size_t)(k0 + kk) * DOUT + cadj + cc);
    tile[kk][cc + 0] = v.x; tile[kk][cc + 1] = v.y;
    tile[kk][cc + 2] = v.z; tile[kk][cc + 3] = v.w;
  }
  __syncthreads();
  {
    const int cc = t >> 3;
    const int kk = (t & 7) * 4;
    ushort4 o;
    o.x = f2bf(tile[kk + 0][cc]); o.y = f2bf(tile[kk + 1][cc]);
    o.z = f2bf(tile[kk + 2][cc]); o.w = f2bf(tile[kk + 3][cc]);
    *(ushort4*)(Wt + (size_t)(c0 + cc) * DIN + k0 + kk) = o;
  }
}

// ---------------- main fused kernel ----------------
__global__ __launch_bounds__(TPB, 4) void gcn_kernel(
    const float* __restrict__ rep,
    const float* __restrict__ adj_mask_in,
    const float* __restrict__ adj_mask_loop,
    const float* __restrict__ maskp,
    const float* __restrict__ b_in,
    const float* __restrict__ w_gate_in,
    const float* __restrict__ b_gate_in,
    const float* __restrict__ w_gate_self,
    const int* __restrict__ arc,
    const int* __restrict__ lab,
    const unsigned short* __restrict__ Wt,
    float* __restrict__ out)
{
  __shared__ __align__(16) char smem[SMEM_BYTES];
  unsigned short* Pin = (unsigned short*)(smem + PIN_OFF);
  unsigned short* Psf = (unsigned short*)(smem + PSF_OFF);
  float* wgi  = (float*)(smem + WGI_OFF);
  float* wgs  = (float*)(smem + WGS_OFF);
  float* winl = (float*)(smem + WINL_OFF);
  float* wsfl = (float*)(smem + WSFL_OFF);
  float* mskl = (float*)(smem + MSKL_OFF);
  int*   hdl  = (int*)(smem + HDL_OFF);
  int*   lbl  = (int*)(smem + LBL_OFF);
  float* gld  = (float*)(smem + GLD_OFF);
  float* amd  = (float*)(smem + AMD_OFF);
  float* ald  = (float*)(smem + ALD_OFF);
  float* bgl  = (float*)(smem + BGL_OFF);

  const int b    = blockIdx.x >> 1;   // sentence
  const int h    = blockIdx.x & 1;    // N-half
  const int t    = threadIdx.x;
  const int w    = t >> 6;            // wave 0..7 (block-local cols w*32..)
  const int lane = t & 63;
  const int nlo  = lane & 15;
  const int quad = lane >> 4;

  // A-staging thread coords: row r, 4-float strip kk within each 32-K chunk
  const int r  = t >> 3;
  const int kk = t & 7;
  const int pa = kk >> 1;             // 16B k-frag within chunk
  const float* arow = rep + (size_t)(b * LTOK + r) * DIN + kk * 4;

  // B-staging per-lane source offsets (shorts), k-piece pre-swizzled:
  // LDS unit j = c*4 + pp holds k-piece (pp ^ (c&3)) of block-local col c.
  const int j0 = w * 128 + lane;
  const int j1 = j0 + 64;
  const int c0 = j0 >> 2, p0 = j0 & 3;
  const int c1 = j1 >> 2, p1 = j1 & 3;
  const int cc0 = c0 + h * 128 + ((c0 >> 7) << 7);   // cat col (in/self regions)
  const int cc1 = c1 + h * 128 + ((c1 >> 7) << 7);
  const size_t boff0 = (size_t)cc0 * DIN + ((p0 ^ (c0 & 3)) << 3);
  const size_t boff1 = (size_t)cc1 * DIN + ((p1 ^ (c1 & 3)) << 3);

  // B-frag read offsets (bytes within a B slot), kc-independent:
  int bofs[2];
  #pragma unroll
  for (int nt = 0; nt < 2; ++nt) {
    const int c = w * 32 + nt * 16 + nlo;
    bofs[nt] = (c * 4 + (quad ^ (c & 3))) << 4;
  }

  f32x4 Ar0, Ar1, Ar2;                // rotation: chunk ch lives in AR(ch%3)
  float si = 0.f, ss = 0.f;

#define AR(k) ((k) == 0 ? Ar0 : (k) == 1 ? Ar1 : Ar2)

#define STAGE_B(ch) do { \
    const unsigned short* _s0 = Wt + boff0 + (size_t)((ch) & 15) * 32; \
    const unsigned short* _s1 = Wt + boff1 + (size_t)((ch) & 15) * 32; \
    char* _d = smem + BBUF_OFF + (((ch) & 1) << 14); \
    __builtin_amdgcn_global_load_lds((const __attribute__((address_space(1))) void*)_s0, \
        (__attribute__((address_space(3))) void*)(_d + ((w * 128 + lane) << 4)), 16, 0, 0); \
    __builtin_amdgcn_global_load_lds((const __attribute__((address_space(1))) void*)_s1, \
        (__attribute__((address_space(3))) void*)(_d + ((w * 128 + 64 + lane) << 4)), 16, 0, 0); \
  } while (0)

  // cvt + fused gate partials + ds_write of chunk (ch) into A slot ch%3.
  // Unit u = pa*64 + (r ^ (4*(ch&7)+pa)); read side uses the same key.
#define PUT_A(ch) do { \
    const f32x4 _v = AR((ch) % 3); \
    const f32x4 _g = *(const f32x4*)(wgi + (ch) * 32 + kk * 4); \
    const f32x4 _h = *(const f32x4*)(wgs + (ch) * 32 + kk * 4); \
    si += _v[0] * _g[0] + _v[1] * _g[1] + _v[2] * _g[2] + _v[3] * _g[3]; \
    ss += _v[0] * _h[0] + _v[1] * _h[1] + _v[2] * _h[2] + _v[3] * _h[3]; \
    ushort4 _o; \
    _o.x = f2bf(_v[0]); _o.y = f2bf(_v[1]); _o.z = f2bf(_v[2]); _o.w = f2bf(_v[3]); \
    const int _u = pa * 64 + (r ^ ((((ch) & 7) << 2) + pa)); \
    *(ushort4*)(smem + ((ch) % 3) * 4096 + _u * 16 + ((kk & 1) << 3)) = _o; \
  } while (0)

  f32x4 acc[4][2];
  #pragma unroll
  for (int i = 0; i < 4; ++i)
    #pragma unroll
    for (int j = 0; j < 2; ++j) {
      f32x4 z = {0.f, 0.f, 0.f, 0.f};
      acc[i][j] = z;
    }

  // ---- prologue ----
  if (t < LTOK) {
    const int m = b * LTOK + t;
    hdl[t] = arc[2 * m + 1];
    lbl[t] = lab[m];
    amd[t] = adj_mask_in[m];
    ald[t] = adj_mask_loop[m];
    mskl[t] = maskp[m];
  }
  if (t < NREL) bgl[t] = b_gate_in[t];
  wgi[t] = w_gate_in[t];
  wgs[t] = w_gate_self[t];

  STAGE_B(0);
  asm volatile("" ::: "memory");      // pin issue order: B0 before A0/A1
  Ar0 = *(const f32x4*)(arow);        // chunk 0
  Ar1 = *(const f32x4*)(arow + 32);   // chunk 1
  asm volatile("s_waitcnt lgkmcnt(0)" ::: "memory");  // wgi/wgs/persist visible
  __builtin_amdgcn_s_barrier();
  __builtin_amdgcn_sched_barrier(0);
  PUT_A(0);                           // compiler inserts exact counted vmcnt for Ar0

  // ---- pipelined K-loop: 16 chunks ----
  #pragma unroll
  for (int kc = 0; kc < 16; ++kc) {
    if (kc < 15) STAGE_B(kc + 1);
    if (kc == 15) {
      asm volatile("s_waitcnt vmcnt(0)" ::: "memory");
    } else {
      asm volatile("s_waitcnt vmcnt(3)" ::: "memory");  // B(kc) complete; rest in flight
    }
    asm volatile("s_waitcnt lgkmcnt(0)" ::: "memory");  // PUT_A(kc) writes visible
    __builtin_amdgcn_s_barrier();
    __builtin_amdgcn_sched_barrier(0);

    if (kc < 14) AR((kc + 2) % 3) = *(const f32x4*)(arow + (kc + 2) * 32);
    if (kc < 15) PUT_A(kc + 1);

    {
      const int sw = (kc & 7) << 2;
      const char* ab = smem + (kc % 3) * 4096;
      const char* bb = smem + BBUF_OFF + ((kc & 1) << 14);
      s16x8 af[4];
      #pragma unroll
      for (int mt = 0; mt < 4; ++mt)
        af[mt] = *(const s16x8*)(ab + ((quad * 64 + ((mt * 16 + nlo) ^ (sw + quad))) << 4));
      s16x8 bfv[2];
      #pragma unroll
      for (int nt = 0; nt < 2; ++nt)
        bfv[nt] = *(const s16x8*)(bb + bofs[nt]);
      __builtin_amdgcn_s_setprio(1);
      #pragma unroll
      for (int nt = 0; nt < 2; ++nt)
        #pragma unroll
        for (int mt = 0; mt < 4; ++mt)
          acc[mt][nt] = __builtin_amdgcn_mfma_f32_16x16x32_bf16(af[mt], bfv[nt], acc[mt][nt], 0, 0, 0);
      __builtin_amdgcn_s_setprio(0);
    }
    __builtin_amdgcn_sched_barrier(0);
    __builtin_amdgcn_s_barrier();     // reads done before next overwrite
  }

  // ---- gate reduce (8 threads per row) ----
  si += __shfl_xor(si, 1, 64); si += __shfl_xor(si, 2, 64); si += __shfl_xor(si, 4, 64);
  ss += __shfl_xor(ss, 1, 64); ss += __shfl_xor(ss, 2, 64); ss += __shfl_xor(ss, 4, 64);
  if ((t & 7) == 0) { gld[r * 2] = si; gld[r * 2 + 1] = ss; }

  asm volatile("s_waitcnt lgkmcnt(0)" ::: "memory");
  __builtin_amdgcn_s_barrier();
  __builtin_amdgcn_sched_barrier(0);

  if (t < LTOK) {
    winl[t] = sigmoidf_(gld[hdl[t] * 2] + bgl[lbl[t]]) * amd[t] * amd[t];
    wsfl[t] = sigmoidf_(gld[t * 2 + 1]) * ald[t] * ald[t];
  }

  // P -> LDS (bf16; staging region is dead). waves 0-3: P_in, 4-7: P_self.
  {
    unsigned short* dst = (w < 4) ? Pin : Psf;
    const int cb = (w & 3) * 32;
    #pragma unroll
    for (int mt = 0; mt < 4; ++mt)
      #pragma unroll
      for (int nt = 0; nt < 2; ++nt)
        #pragma unroll
        for (int rr = 0; rr < 4; ++rr)
          dst[(mt * 16 + quad * 4 + rr) * PSTR + cb + nt * 16 + nlo] = f2bf(acc[mt][nt][rr]);
  }
  asm volatile("s_waitcnt lgkmcnt(0)" ::: "memory");
  __builtin_amdgcn_s_barrier();

  // out = relu((Pin[hd] + b_in[lb]) * w_in + Psf[row] * w_self) * mask
  #pragma unroll
  for (int i = 0; i < 4; ++i) {
    const int q   = i * TPB + t;
    const int row = q >> 5;
    const int cl  = (q & 31) * 4;
    const int hd  = hdl[row];
    const int lb  = lbl[row];
    const float wi = winl[row], wsv = wsfl[row], mk = mskl[row];
    const float4  bi = *(const float4*)(b_in + lb * DOUT + h * 128 + cl);
    const ushort4 pi = *(const ushort4*)(Pin + hd * PSTR + cl);
    const ushort4 ps = *(const ushort4*)(Psf + row * PSTR + cl);
    float4 v;
    v.x = (bf2f(pi.x) + bi.x) * wi + bf2f(ps.x) * wsv;
    v.y = (bf2f(pi.y) + bi.y) * wi + bf2f(ps.y) * wsv;
    v.z = (bf2f(pi.z) + bi.z) * wi + bf2f(ps.z) * wsv;
    v.w = (bf2f(pi.w) + bi.w) * wi + bf2f(ps.w) * wsv;
    v.x = fmaxf(v.x, 0.f) * mk; v.y = fmaxf(v.y, 0.f) * mk;
    v.z = fmaxf(v.z, 0.f) * mk; v.w = fmaxf(v.w, 0.f) * mk;
    *(float4*)(out + (size_t)(b * LTOK + row) * DOUT + h * 128 + cl) = v;
  }
#undef AR
#undef STAGE_B
#undef PUT_A
}

extern "C" void kernel_launch(void* const* d_in, const int* in_sizes, int n_in,
                              void* d_out, int out_size, void* d_ws, size_t ws_size,
                              hipStream_t stream) {
  const float* rep           = (const float*)d_in[0];
  const float* adj_mask_in   = (const float*)d_in[1];
  const float* adj_mask_loop = (const float*)d_in[2];
  const float* mask          = (const float*)d_in[3];
  const float* W_in          = (const float*)d_in[4];
  const float* b_in          = (const float*)d_in[5];
  const float* W_gate_in     = (const float*)d_in[6];
  const float* b_gate_in     = (const float*)d_in[7];
  const float* W_self        = (const float*)d_in[8];
  const float* W_gate_self   = (const float*)d_in[9];
  const int*   arc           = (const int*)d_in[10];
  const int*   lab           = (const int*)d_in[11];
  float* out = (float*)d_out;
  unsigned short* Wt = (unsigned short*)d_ws;   // [512][512] bf16, 512 KB

  wprep_kernel<<<256, 256, 0, stream>>>(W_in, W_self, Wt);
  gcn_kernel<<<BNK * 2, TPB, 0, stream>>>(rep, adj_mask_in, adj_mask_loop, mask, b_in,
                                          W_gate_in, b_gate_in, W_gate_self, arc, lab, Wt, out);
}